// Round 12
// baseline (221.336 us; speedup 1.0000x reference)
//
#include <hip/hip_runtime.h>
#include <hip/hip_bf16.h>
#include <stdint.h>

#define H_DIM 4096
#define I_DIM 11008
#define NGH   32          // H/128 groups (gate/up)
#define NGI   86          // I/128 groups (down)
#define KWH   512         // packed words per gate/up row (H/8)
#define KWI   1376        // packed words per down row (I/8)
#define NWV   5636096     // packed words per matrix

typedef __attribute__((ext_vector_type(8))) short short8;
typedef __attribute__((ext_vector_type(4))) short s16x4;
typedef __attribute__((ext_vector_type(4))) float f32x4;
typedef __attribute__((ext_vector_type(4))) int   i32x4;

static __device__ __forceinline__ short f2bf(float f) {
  union { __hip_bfloat16 b; short s; } u;
  u.b = __float2bfloat16(f);
  return u.s;
}

// ---- pack one 16-row x 256-int tile -> fragment-ordered pkT[rt][kw][ri] ----
static __device__ __forceinline__ void pack_tile(
    char* smem, const int* __restrict__ src, int RL, int KW,
    int* __restrict__ dstM, int tile)
{
  unsigned short (*sb)[72] = (unsigned short(*)[72])smem;  // stride 72us: low conflict
  int rt, ct;
  if (RL == H_DIM) { rt = tile >> 4; ct = tile & 15; }     // gate/up: 688 x 16
  else             { rt = tile / 43; ct = tile - rt * 43; } // down: 256 x 43
  const int t = threadIdx.x & 255;
  const int rowl = t >> 4, j = t & 15;
  const int* rp = src + (size_t)(rt * 16 + rowl) * RL + ct * 256;
#pragma unroll
  for (int p = 0; p < 4; ++p) {
    i32x4 v = *(const i32x4*)(rp + p * 64 + j * 4);
    sb[rowl][p * 16 + j] = (unsigned short)((v[0] & 15) | ((v[1] & 15) << 4)
                        | ((v[2] & 15) << 8) | ((v[3] & 15) << 12));
  }
  __syncthreads();
  int* dst = dstM + ((size_t)rt * KW + ct * 32) * 16;
#pragma unroll
  for (int p = 0; p < 2; ++p) {
    const int wi = t + p * 256;
    const int kwl = wi >> 4, ri = wi & 15;
    dst[wi] = (int)sb[ri][2 * kwl] | ((int)sb[ri][2 * kwl + 1] << 16);
  }
}

// ---- 32-row GEMM body with A-reuse (gate: UP=0 -> f32 gsum; up: UP=1 swiglu->hb)
template<int UP>
static __device__ __forceinline__ void gemm_gu_body(
    char* smem, const short* __restrict__ xb, const int* __restrict__ pktM,
    const float* __restrict__ sc, const float* __restrict__ ze,
    float* __restrict__ gsum, short* __restrict__ hb, int rtb)
{
  float (*red)[4][4][64] = (float(*)[4][4][64])smem;   // [8][4][4][64] = 32 KB
  const int n0   = rtb * 32;
  const int w    = threadIdx.x >> 6;
  const int l    = threadIdx.x & 63;
  const int col  = l & 15;
  const int krow = l >> 4;

  const int* B0 = pktM + (size_t)(2 * rtb)     * (KWH * 16) + col;
  const int* B1 = pktM + (size_t)(2 * rtb + 1) * (KWH * 16) + col;

  float sv[2][4], zv[2][4];
#pragma unroll
  for (int cg = 0; cg < 2; ++cg) {
    const int i = n0 + cg * 16 + col;
#pragma unroll
    for (int g = 0; g < 4; ++g) {
      const int gg = w * 4 + g;
      sv[cg][g] = sc[(size_t)i * NGH + gg];
      zv[cg][g] = ze[(size_t)i * NGH + gg] * sv[cg][g];
    }
  }

  f32x4 acc[2][4];
#pragma unroll
  for (int cg = 0; cg < 2; ++cg)
#pragma unroll
    for (int c = 0; c < 4; ++c)
#pragma unroll
      for (int r = 0; r < 4; ++r) acc[cg][c][r] = 0.f;

  const int wb  = w * 64;
  const int ks0 = w * 512 + krow * 8;

  int q0A = B0[(wb + krow) * 16], q1A = B1[(wb + krow) * 16];
  int q0B, q1B;
  short8 aA[4], aB[4];
#pragma unroll
  for (int c = 0; c < 4; ++c)
    aA[c] = *(const short8*)(xb + (size_t)(c * 16 + col) * H_DIM + ks0);

#pragma unroll
  for (int u = 0; u < 8; ++u) {
    const int t1 = 2 * u + 1;
    const int t2 = (2 * u + 2) & 15;   // wraps on last (harmless)
    const int g  = u >> 1;
    q0B = B0[(wb + 4 * t1 + krow) * 16];
    q1B = B1[(wb + 4 * t1 + krow) * 16];
#pragma unroll
    for (int c = 0; c < 4; ++c)
      aB[c] = *(const short8*)(xb + (size_t)(c * 16 + col) * H_DIM + ks0 + t1 * 32);
    {
      short8 b0, b1;
#pragma unroll
      for (int j = 0; j < 8; ++j) {
        b0[j] = f2bf((float)((q0A >> (4 * j)) & 15) * sv[0][g] - zv[0][g]);
        b1[j] = f2bf((float)((q1A >> (4 * j)) & 15) * sv[1][g] - zv[1][g]);
      }
#pragma unroll
      for (int c = 0; c < 4; ++c) {
        acc[0][c] = __builtin_amdgcn_mfma_f32_16x16x32_bf16(aA[c], b0, acc[0][c], 0, 0, 0);
        acc[1][c] = __builtin_amdgcn_mfma_f32_16x16x32_bf16(aA[c], b1, acc[1][c], 0, 0, 0);
      }
    }
    q0A = B0[(wb + 4 * t2 + krow) * 16];
    q1A = B1[(wb + 4 * t2 + krow) * 16];
#pragma unroll
    for (int c = 0; c < 4; ++c)
      aA[c] = *(const short8*)(xb + (size_t)(c * 16 + col) * H_DIM + ks0 + t2 * 32);
    {
      short8 b0, b1;
#pragma unroll
      for (int j = 0; j < 8; ++j) {
        b0[j] = f2bf((float)((q0B >> (4 * j)) & 15) * sv[0][g] - zv[0][g]);
        b1[j] = f2bf((float)((q1B >> (4 * j)) & 15) * sv[1][g] - zv[1][g]);
      }
#pragma unroll
      for (int c = 0; c < 4; ++c) {
        acc[0][c] = __builtin_amdgcn_mfma_f32_16x16x32_bf16(aB[c], b0, acc[0][c], 0, 0, 0);
        acc[1][c] = __builtin_amdgcn_mfma_f32_16x16x32_bf16(aB[c], b1, acc[1][c], 0, 0, 0);
      }
    }
  }

  const int c2 = threadIdx.x >> 7;
  const int rh = (threadIdx.x >> 6) & 1;
  const int ll = threadIdx.x & 63;
#pragma unroll
  for (int cg = 0; cg < 2; ++cg) {
#pragma unroll
    for (int c = 0; c < 4; ++c)
#pragma unroll
      for (int r = 0; r < 4; ++r)
        red[w][c][r][l] = acc[cg][c][r];
    __syncthreads();
#pragma unroll
    for (int rr = 0; rr < 2; ++rr) {
      const int r = rh * 2 + rr;
      float s = 0.f;
#pragma unroll
      for (int ww = 0; ww < 8; ++ww) s += red[ww][c2][r][ll];
      const int m  = c2 * 16 + (ll >> 4) * 4 + r;     // C/D: row=(l>>4)*4+r
      const int ii = n0 + cg * 16 + (ll & 15);        //      col=l&15
      if (UP) {
        const float gv = gsum[(size_t)m * I_DIM + ii];
        const float hv = gv / (1.f + __expf(-gv)) * s;   // silu(g)*u
        hb[(size_t)m * I_DIM + ii] = f2bf(hv);
      } else {
        gsum[(size_t)m * I_DIM + ii] = s;
      }
    }
    if (cg == 0) __syncthreads();   // red reuse fence
  }
}

// ---- launch 1: xcvt (blocks 0-127) + pack gate (5504 blocks x 2 tiles) ----
__global__ __launch_bounds__(512, 4) void packG_xcvt_kernel(
    const float* __restrict__ x, short* __restrict__ xb,
    const int* __restrict__ gq, int* __restrict__ gp)
{
  __shared__ char smem[4608];
  if (blockIdx.x < 128) {
    const int i = (blockIdx.x * 512 + threadIdx.x) * 4;
    f32x4 v = *(const f32x4*)(x + i);
    s16x4 o;
    o[0] = f2bf(v[0]); o[1] = f2bf(v[1]); o[2] = f2bf(v[2]); o[3] = f2bf(v[3]);
    *(s16x4*)(xb + i) = o;
    return;
  }
  const int pb = blockIdx.x - 128;
  const int half = threadIdx.x >> 8;
  pack_tile(smem + half * 2304, gq, H_DIM, KWH, gp, pb * 2 + half);
}

// ---- launch 2: gate GEMM (344 tiles, interleaved) || pack up (5504) ----
// Block map: j<688: even -> GEMM j/2, odd -> pack (j-1)/2;  j>=688 -> pack j-344.
__global__ __launch_bounds__(512, 4) void gateU_kernel(
    const short* __restrict__ xb, const int* __restrict__ gp,
    const float* __restrict__ gsc, const float* __restrict__ gze,
    float* __restrict__ gsum, const int* __restrict__ uq, int* __restrict__ upk)
{
  __shared__ char smem[32768];
  const int j = blockIdx.x;
  if (j < 688 && (j & 1) == 0) {
    gemm_gu_body<0>(smem, xb, gp, gsc, gze, gsum, nullptr, j >> 1);
    return;
  }
  const int pb = (j < 688) ? (j >> 1) : (j - 344);
  const int half = threadIdx.x >> 8;
  pack_tile(smem + half * 2304, uq, H_DIM, KWH, upk, pb * 2 + half);
}

// ---- launch 3: up GEMM+SwiGLU (344 tiles, interleaved) || pack down (5504) ----
__global__ __launch_bounds__(512, 4) void upD_kernel(
    const short* __restrict__ xb, const int* __restrict__ upk,
    const float* __restrict__ usc, const float* __restrict__ uze,
    float* __restrict__ gsum, short* __restrict__ hb,
    const int* __restrict__ dq, int* __restrict__ dpk)
{
  __shared__ char smem[32768];
  const int j = blockIdx.x;
  if (j < 688 && (j & 1) == 0) {
    gemm_gu_body<1>(smem, xb, upk, usc, uze, gsum, hb, j >> 1);
    return;
  }
  const int pb = (j < 688) ? (j >> 1) : (j - 344);
  const int half = threadIdx.x >> 8;
  pack_tile(smem + half * 2304, dq, I_DIM, KWI, dpk, pb * 2 + half);
}

// ---- launch 4: down GEMM, split-K x4 (transposed-packed) ----
__global__ __launch_bounds__(512, 4) void phase2p_kernel(
    const short* __restrict__ hb, const int* __restrict__ dpt,
    const float* __restrict__ dsc, const float* __restrict__ dze,
    float* __restrict__ part)
{
  __shared__ float red[8][4][4][64];   // 32 KB
  const int tile  = blockIdx.x & 255;
  const int split = blockIdx.x >> 8;
  const int n0   = tile * 16;
  const int w    = threadIdx.x >> 6;
  const int l    = threadIdx.x & 63;
  const int col  = l & 15;
  const int krow = l >> 4;
  const int n    = n0 + col;

  const int* dB = dpt + (size_t)tile * (KWI * 16) + col;

  f32x4 acc[4];
#pragma unroll
  for (int c = 0; c < 4; ++c)
#pragma unroll
    for (int r = 0; r < 4; ++r) acc[c][r] = 0.f;

  const int cnt    = (w < 6) ? 11 : 10;
  const int sstart = (w < 6) ? w * 11 : 66 + (w - 6) * 10;
  const int kbase  = split * 2752 + sstart * 32;
  const int wbase  = split * 344 + sstart * 4;

  const int g0 = kbase >> 7;
  float s0 = dsc[(size_t)n * NGI + g0];
  float s1 = dsc[(size_t)n * NGI + min(g0 + 1, NGI - 1)];
  float s2 = dsc[(size_t)n * NGI + min(g0 + 2, NGI - 1)];
  float s3 = dsc[(size_t)n * NGI + min(g0 + 3, NGI - 1)];
  float z0 = dze[(size_t)n * NGI + g0] * s0;
  float z1 = dze[(size_t)n * NGI + min(g0 + 1, NGI - 1)] * s1;
  float z2 = dze[(size_t)n * NGI + min(g0 + 2, NGI - 1)] * s2;
  float z3 = dze[(size_t)n * NGI + min(g0 + 3, NGI - 1)] * s3;

  int qdA = dB[(wbase + krow) * 16], qdB_;
  short8 aA[4], aB[4];
#pragma unroll
  for (int c = 0; c < 4; ++c)
    aA[c] = *(const short8*)(hb + (size_t)(c * 16 + col) * I_DIM + kbase + krow * 8);

  const int nh = cnt >> 1;
#pragma unroll 1
  for (int u = 0; u < nh; ++u) {
    const int t0 = 2 * u, t1 = 2 * u + 1;
    const int t2 = (t1 + 1 < cnt) ? (t1 + 1) : 0;
    qdB_ = dB[(wbase + 4 * t1 + krow) * 16];
#pragma unroll
    for (int c = 0; c < 4; ++c)
      aB[c] = *(const short8*)(hb + (size_t)(c * 16 + col) * I_DIM + kbase + t1 * 32 + krow * 8);
    {
      const int gi = ((kbase + t0 * 32) >> 7) - g0;
      const float sv = gi == 0 ? s0 : gi == 1 ? s1 : gi == 2 ? s2 : s3;
      const float zv = gi == 0 ? z0 : gi == 1 ? z1 : gi == 2 ? z2 : z3;
      short8 b;
#pragma unroll
      for (int j = 0; j < 8; ++j)
        b[j] = f2bf((float)((qdA >> (4 * j)) & 15) * sv - zv);
#pragma unroll
      for (int c = 0; c < 4; ++c)
        acc[c] = __builtin_amdgcn_mfma_f32_16x16x32_bf16(aA[c], b, acc[c], 0, 0, 0);
    }
    qdA = dB[(wbase + 4 * t2 + krow) * 16];
#pragma unroll
    for (int c = 0; c < 4; ++c)
      aA[c] = *(const short8*)(hb + (size_t)(c * 16 + col) * I_DIM + kbase + t2 * 32 + krow * 8);
    {
      const int gi = ((kbase + t1 * 32) >> 7) - g0;
      const float sv = gi == 0 ? s0 : gi == 1 ? s1 : gi == 2 ? s2 : s3;
      const float zv = gi == 0 ? z0 : gi == 1 ? z1 : gi == 2 ? z2 : z3;
      short8 b;
#pragma unroll
      for (int j = 0; j < 8; ++j)
        b[j] = f2bf((float)((qdB_ >> (4 * j)) & 15) * sv - zv);
#pragma unroll
      for (int c = 0; c < 4; ++c)
        acc[c] = __builtin_amdgcn_mfma_f32_16x16x32_bf16(aB[c], b, acc[c], 0, 0, 0);
    }
  }
  if (cnt & 1) {
    const int t0 = cnt - 1;
    const int gi = ((kbase + t0 * 32) >> 7) - g0;
    const float sv = gi == 0 ? s0 : gi == 1 ? s1 : gi == 2 ? s2 : s3;
    const float zv = gi == 0 ? z0 : gi == 1 ? z1 : gi == 2 ? z2 : z3;
    short8 b;
#pragma unroll
    for (int j = 0; j < 8; ++j)
      b[j] = f2bf((float)((qdA >> (4 * j)) & 15) * sv - zv);
#pragma unroll
    for (int c = 0; c < 4; ++c)
      acc[c] = __builtin_amdgcn_mfma_f32_16x16x32_bf16(aA[c], b, acc[c], 0, 0, 0);
  }

#pragma unroll
  for (int c = 0; c < 4; ++c)
#pragma unroll
    for (int r = 0; r < 4; ++r)
      red[w][c][r][l] = acc[c][r];
  __syncthreads();

  if (threadIdx.x < 256) {
    const int c2 = threadIdx.x >> 6;
    const int ll = threadIdx.x & 63;
    float* po = part + (size_t)split * (64 * H_DIM);
#pragma unroll
    for (int r = 0; r < 4; ++r) {
      float s = 0.f;
#pragma unroll
      for (int ww = 0; ww < 8; ++ww) s += red[ww][c2][r][ll];
      const int m  = c2 * 16 + (ll >> 4) * 4 + r;
      const int nn = n0 + (ll & 15);
      po[(size_t)m * H_DIM + nn] = s;
    }
  }
}

__global__ void reduce4_kernel(const float* __restrict__ part, float* __restrict__ out) {
  const int idx = (blockIdx.x * 256 + threadIdx.x) * 4;
  const int S = 64 * H_DIM;
  f32x4 s0 = *(const f32x4*)(part + idx);
  f32x4 s1 = *(const f32x4*)(part + S + idx);
  f32x4 s2 = *(const f32x4*)(part + 2 * S + idx);
  f32x4 s3 = *(const f32x4*)(part + 3 * S + idx);
  f32x4 r = (s0 + s1) + (s2 + s3);
  *(f32x4*)(out + idx) = r;
}

// ---------------- fallback (raw-weight) kernels, used if ws too small --------
__global__ void xcvt_kernel(const float* __restrict__ x, short* __restrict__ xb) {
  int i = (blockIdx.x * 256 + threadIdx.x) * 4;
  f32x4 v = *(const f32x4*)(x + i);
  s16x4 o;
  o[0] = f2bf(v[0]); o[1] = f2bf(v[1]); o[2] = f2bf(v[2]); o[3] = f2bf(v[3]);
  *(s16x4*)(xb + i) = o;
}

__global__ __launch_bounds__(512, 4) void phase1f_kernel(
    const short* __restrict__ xb,
    const int* __restrict__ gq, const float* __restrict__ gsc, const float* __restrict__ gze,
    const int* __restrict__ uq, const float* __restrict__ usc, const float* __restrict__ uze,
    short* __restrict__ hb)
{
  __shared__ float red[8][4][4][64];
  const int n0   = blockIdx.x * 16;
  const int w    = threadIdx.x >> 6;
  const int l    = threadIdx.x & 63;
  const int col  = l & 15;
  const int krow = l >> 4;
  const int i    = n0 + col;
  const int*   gqr = gq + (size_t)i * H_DIM;
  const int*   uqr = uq + (size_t)i * H_DIM;
  const float* gsr = gsc + (size_t)i * NGH;
  const float* gzr = gze + (size_t)i * NGH;
  const float* usr = usc + (size_t)i * NGH;
  const float* uzr = uze + (size_t)i * NGH;
  f32x4 accG[4], accU[4];
#pragma unroll
  for (int c = 0; c < 4; ++c)
#pragma unroll
    for (int r = 0; r < 4; ++r) { accG[c][r] = 0.f; accU[c][r] = 0.f; }
  const int kw = w * 512;
#pragma unroll 1
  for (int g = 0; g < 4; ++g) {
    const int gg = w * 4 + g;
    const float sg = gsr[gg], zg = gzr[gg] * sg;
    const float su = usr[gg], zu = uzr[gg] * su;
#pragma unroll
    for (int ks = 0; ks < 4; ++ks) {
      const int koff = kw + g * 128 + ks * 32 + krow * 8;
      i32x4 q0 = *(const i32x4*)(gqr + koff);
      i32x4 q1 = *(const i32x4*)(gqr + koff + 4);
      i32x4 p0 = *(const i32x4*)(uqr + koff);
      i32x4 p1 = *(const i32x4*)(uqr + koff + 4);
      short8 a[4];
#pragma unroll
      for (int c = 0; c < 4; ++c)
        a[c] = *(const short8*)(xb + (size_t)(c * 16 + col) * H_DIM + koff);
      short8 bg, bu;
#pragma unroll
      for (int j = 0; j < 4; ++j) {
        bg[j]     = f2bf((float)q0[j] * sg - zg);
        bg[j + 4] = f2bf((float)q1[j] * sg - zg);
        bu[j]     = f2bf((float)p0[j] * su - zu);
        bu[j + 4] = f2bf((float)p1[j] * su - zu);
      }
#pragma unroll
      for (int c = 0; c < 4; ++c) {
        accG[c] = __builtin_amdgcn_mfma_f32_16x16x32_bf16(a[c], bg, accG[c], 0, 0, 0);
        accU[c] = __builtin_amdgcn_mfma_f32_16x16x32_bf16(a[c], bu, accU[c], 0, 0, 0);
      }
    }
  }
  const int c2 = threadIdx.x >> 7;
  const int rh = (threadIdx.x >> 6) & 1;
  const int ll = threadIdx.x & 63;
#pragma unroll
  for (int c = 0; c < 4; ++c)
#pragma unroll
    for (int r = 0; r < 4; ++r)
      red[w][c][r][l] = accG[c][r];
  __syncthreads();
  float gsum[2];
#pragma unroll
  for (int rr = 0; rr < 2; ++rr) {
    const int r = rh * 2 + rr;
    float s = 0.f;
#pragma unroll
    for (int ww = 0; ww < 8; ++ww) s += red[ww][c2][r][ll];
    gsum[rr] = s;
  }
  __syncthreads();
#pragma unroll
  for (int c = 0; c < 4; ++c)
#pragma unroll
    for (int r = 0; r < 4; ++r)
      red[w][c][r][l] = accU[c][r];
  __syncthreads();
#pragma unroll
  for (int rr = 0; rr < 2; ++rr) {
    const int r = rh * 2 + rr;
    float us = 0.f;
#pragma unroll
    for (int ww = 0; ww < 8; ++ww) us += red[ww][c2][r][ll];
    const float gv = gsum[rr];
    const float hv = gv / (1.f + __expf(-gv)) * us;
    const int m  = c2 * 16 + (ll >> 4) * 4 + r;
    const int ii = n0 + (ll & 15);
    hb[(size_t)m * I_DIM + ii] = f2bf(hv);
  }
}

__global__ __launch_bounds__(512, 4) void phase2f_kernel(
    const short* __restrict__ hb,
    const int* __restrict__ dq, const float* __restrict__ dsc, const float* __restrict__ dze,
    float* __restrict__ part)
{
  __shared__ float red[8][4][4][64];
  const int tile  = blockIdx.x & 255;
  const int split = blockIdx.x >> 8;
  const int n0   = tile * 16;
  const int w    = threadIdx.x >> 6;
  const int l    = threadIdx.x & 63;
  const int col  = l & 15;
  const int krow = l >> 4;
  const int n    = n0 + col;
  const int*   dqr = dq + (size_t)n * I_DIM;
  const float* dsr = dsc + (size_t)n * NGI;
  const float* dzr = dze + (size_t)n * NGI;
  f32x4 acc[4];
#pragma unroll
  for (int c = 0; c < 4; ++c)
#pragma unroll
    for (int r = 0; r < 4; ++r) acc[c][r] = 0.f;
  const int cnt    = (w < 6) ? 11 : 10;
  const int sstart = (w < 6) ? w * 11 : 66 + (w - 6) * 10;
  const int kbase  = split * 2752 + sstart * 32;
  int gprev = -1;
  float sv = 0.f, zv = 0.f;
#pragma unroll 1
  for (int s = 0; s < cnt; ++s) {
    const int k0 = kbase + s * 32;
    const int g  = k0 >> 7;
    if (g != gprev) { sv = dsr[g]; zv = dzr[g] * sv; gprev = g; }
    i32x4 q0 = *(const i32x4*)(dqr + k0 + krow * 8);
    i32x4 q1 = *(const i32x4*)(dqr + k0 + krow * 8 + 4);
    short8 a[4];
#pragma unroll
    for (int c = 0; c < 4; ++c)
      a[c] = *(const short8*)(hb + (size_t)(c * 16 + col) * I_DIM + k0 + krow * 8);
    short8 b;
#pragma unroll
    for (int j = 0; j < 4; ++j) {
      b[j]     = f2bf((float)q0[j] * sv - zv);
      b[j + 4] = f2bf((float)q1[j] * sv - zv);
    }
#pragma unroll
    for (int c = 0; c < 4; ++c)
      acc[c] = __builtin_amdgcn_mfma_f32_16x16x32_bf16(a[c], b, acc[c], 0, 0, 0);
  }
#pragma unroll
  for (int c = 0; c < 4; ++c)
#pragma unroll
    for (int r = 0; r < 4; ++r)
      red[w][c][r][l] = acc[c][r];
  __syncthreads();
  if (threadIdx.x < 256) {
    const int c2 = threadIdx.x >> 6;
    const int ll = threadIdx.x & 63;
    float* po = part + (size_t)split * (64 * H_DIM);
#pragma unroll
    for (int r = 0; r < 4; ++r) {
      float s = 0.f;
#pragma unroll
      for (int ww = 0; ww < 8; ++ww) s += red[ww][c2][r][ll];
      const int m  = c2 * 16 + (ll >> 4) * 4 + r;
      const int nn = n0 + (ll & 15);
      po[(size_t)m * H_DIM + nn] = s;
    }
  }
}

extern "C" void kernel_launch(void* const* d_in, const int* in_sizes, int n_in,
                              void* d_out, int out_size, void* d_ws, size_t ws_size,
                              hipStream_t stream) {
  const float* x  = (const float*)d_in[0];
  const int*   gq = (const int*)d_in[1];
  const float* gs = (const float*)d_in[2];
  const float* gz = (const float*)d_in[3];
  const int*   uq = (const int*)d_in[4];
  const float* us = (const float*)d_in[5];
  const float* uz = (const float*)d_in[6];
  const int*   dq = (const int*)d_in[7];
  const float* ds = (const float*)d_in[8];
  const float* dz = (const float*)d_in[9];
  float* out = (float*)d_out;

  const size_t XB   = (size_t)64 * H_DIM * 2;          // 512 KB
  const size_t HB   = (size_t)64 * I_DIM * 2;          // 1.376 MB
  const size_t PART = (size_t)4 * 64 * H_DIM * 4;      // 4 MB (gsum reuse in L2/L3)
  const size_t PK   = (size_t)NWV * 4;                 // 22.5 MB each

  short* xb   = (short*)d_ws;
  short* hb   = (short*)((char*)d_ws + XB);
  float* part = (float*)((char*)d_ws + XB + HB);       // gsum during launches 2-3
  int*   pkt  = (int*)((char*)d_ws + XB + HB + PART);
  int*   gp   = pkt;
  int*   upk  = pkt + (size_t)NWV;
  int*   dpk  = pkt + 2 * (size_t)NWV;

  if (ws_size >= XB + HB + PART + 3 * PK) {
    packG_xcvt_kernel<<<128 + 5504, 512, 0, stream>>>(x, xb, gq, gp);
    gateU_kernel<<<344 + 5504, 512, 0, stream>>>(xb, gp, gs, gz, part, uq, upk);
    upD_kernel<<<344 + 5504, 512, 0, stream>>>(xb, upk, us, uz, part, hb, dq, dpk);
    phase2p_kernel<<<(H_DIM / 16) * 4, 512, 0, stream>>>(hb, dpk, ds, dz, part);
  } else {
    xcvt_kernel<<<(64 * H_DIM) / 1024, 256, 0, stream>>>(x, xb);
    phase1f_kernel<<<I_DIM / 16, 512, 0, stream>>>(xb, gq, gs, gz, uq, us, uz, hb);
    phase2f_kernel<<<(H_DIM / 16) * 4, 512, 0, stream>>>(hb, dq, ds, dz, part);
  }
  reduce4_kernel<<<(64 * H_DIM) / 1024, 256, 0, stream>>>(part, out);
}

// Round 15
// 216.258 us; speedup vs baseline: 1.0235x; 1.0235x over previous
//
#include <hip/hip_runtime.h>
#include <hip/hip_bf16.h>
#include <stdint.h>

#define H_DIM 4096
#define I_DIM 11008
#define NGH   32          // H/128 groups (gate/up)
#define NGI   86          // I/128 groups (down)
#define KWH   512         // packed words per gate/up row (H/8)
#define KWI   1376        // packed words per down row (I/8)
#define NWV   5636096     // packed words per matrix

typedef __attribute__((ext_vector_type(8))) short short8;
typedef __attribute__((ext_vector_type(4))) short s16x4;
typedef __attribute__((ext_vector_type(4))) float f32x4;
typedef __attribute__((ext_vector_type(4))) int   i32x4;

static __device__ __forceinline__ short f2bf(float f) {
  union { __hip_bfloat16 b; short s; } u;
  u.b = __float2bfloat16(f);
  return u.s;
}

// ---- packall: nibble-pack+transpose all 3 matrices, xcvt folded in ----
// blocks 0..33023: pack tiles (16 rows x 256 ints -> pkT[rt][kw][ri]);
// blocks 33024..33279: x -> bf16.
__global__ __launch_bounds__(256) void packall_kernel(
    const int* __restrict__ gq, const int* __restrict__ uq, const int* __restrict__ dq,
    int* __restrict__ pkt, const float* __restrict__ x, short* __restrict__ xb)
{
  __shared__ unsigned short sb[16][72];   // stride 72us: low bank conflicts
  int bid = blockIdx.x;
  if (bid >= 33024) {                      // xcvt tail blocks
    const int i = ((bid - 33024) * 256 + threadIdx.x) * 4;
    f32x4 v = *(const f32x4*)(x + i);
    s16x4 o;
    o[0] = f2bf(v[0]); o[1] = f2bf(v[1]); o[2] = f2bf(v[2]); o[3] = f2bf(v[3]);
    *(s16x4*)(xb + i) = o;
    return;
  }
  const int* src; int RL, KW; size_t obase; int rt, ct;
  if (bid < 11008) {                       // gate: 688 rt x 16 ct
    src = gq; RL = H_DIM; KW = KWH; obase = 0;
    rt = bid >> 4; ct = bid & 15;
  } else if (bid < 22016) {                // up
    src = uq; RL = H_DIM; KW = KWH; obase = (size_t)NWV;
    bid -= 11008; rt = bid >> 4; ct = bid & 15;
  } else {                                 // down: 256 rt x 43 ct
    src = dq; RL = I_DIM; KW = KWI; obase = 2 * (size_t)NWV;
    bid -= 22016; rt = bid / 43; ct = bid - rt * 43;
  }
  const int t = threadIdx.x;
  const int rowl = t >> 4, j = t & 15;
  const int* rp = src + (size_t)(rt * 16 + rowl) * RL + ct * 256;
#pragma unroll
  for (int p = 0; p < 4; ++p) {
    i32x4 v = *(const i32x4*)(rp + p * 64 + j * 4);
    sb[rowl][p * 16 + j] = (unsigned short)((v[0] & 15) | ((v[1] & 15) << 4)
                        | ((v[2] & 15) << 8) | ((v[3] & 15) << 12));
  }
  __syncthreads();
  int* dst = pkt + obase + ((size_t)rt * KW + ct * 32) * 16;
#pragma unroll
  for (int p = 0; p < 2; ++p) {
    const int wi = t + p * 256;
    const int kwl = wi >> 4, ri = wi & 15;
    dst[wi] = (int)sb[ri][2 * kwl] | ((int)sb[ri][2 * kwl + 1] << 16);
  }
}

// ---- fused gate+up GEMM + SwiGLU. 344 blocks x 512 thr (8 waves).
// Block: 32 I-rows (2 col-groups). Wave w: K-seg of 512 ints, computes BOTH
// projections (shared A-frags). 2-deep register pipeline. No gsum round-trip.
__global__ __launch_bounds__(512, 2) void gemm_gu_fused(
    const short* __restrict__ xb,
    const int* __restrict__ gp, const int* __restrict__ upk,
    const float* __restrict__ gsc, const float* __restrict__ gze,
    const float* __restrict__ usc, const float* __restrict__ uze,
    short* __restrict__ hb)
{
  __shared__ float red[8][4][4][64];   // 32 KB
  const int rtb  = blockIdx.x;
  const int n0   = rtb * 32;
  const int w    = threadIdx.x >> 6;
  const int l    = threadIdx.x & 63;
  const int col  = l & 15;
  const int krow = l >> 4;

  const int* Bg0 = gp  + (size_t)(2 * rtb)     * (KWH * 16) + col;
  const int* Bg1 = gp  + (size_t)(2 * rtb + 1) * (KWH * 16) + col;
  const int* Bu0 = upk + (size_t)(2 * rtb)     * (KWH * 16) + col;
  const int* Bu1 = upk + (size_t)(2 * rtb + 1) * (KWH * 16) + col;

  float sg[2][4], zg[2][4], su[2][4], zu[2][4];
#pragma unroll
  for (int cg = 0; cg < 2; ++cg) {
    const int i = n0 + cg * 16 + col;
#pragma unroll
    for (int g = 0; g < 4; ++g) {
      const int gg = w * 4 + g;
      sg[cg][g] = gsc[(size_t)i * NGH + gg];
      zg[cg][g] = gze[(size_t)i * NGH + gg] * sg[cg][g];
      su[cg][g] = usc[(size_t)i * NGH + gg];
      zu[cg][g] = uze[(size_t)i * NGH + gg] * su[cg][g];
    }
  }

  f32x4 accG[2][4], accU[2][4];
#pragma unroll
  for (int cg = 0; cg < 2; ++cg)
#pragma unroll
    for (int c = 0; c < 4; ++c)
#pragma unroll
      for (int r = 0; r < 4; ++r) { accG[cg][c][r] = 0.f; accU[cg][c][r] = 0.f; }

  const int wb  = w * 64;
  const int ks0 = w * 512 + krow * 8;

  int g0A = Bg0[(wb + krow) * 16], g1A = Bg1[(wb + krow) * 16];
  int u0A = Bu0[(wb + krow) * 16], u1A = Bu1[(wb + krow) * 16];
  int g0B, g1B, u0B, u1B;
  short8 aA[4], aB[4];
#pragma unroll
  for (int c = 0; c < 4; ++c)
    aA[c] = *(const short8*)(xb + (size_t)(c * 16 + col) * H_DIM + ks0);

#pragma unroll
  for (int u = 0; u < 8; ++u) {
    const int t1 = 2 * u + 1;
    const int t2 = (2 * u + 2) & 15;   // wraps on last (harmless in-bounds)
    const int g  = u >> 1;
    // issue t1 -> B buffers
    g0B = Bg0[(wb + 4 * t1 + krow) * 16];
    g1B = Bg1[(wb + 4 * t1 + krow) * 16];
    u0B = Bu0[(wb + 4 * t1 + krow) * 16];
    u1B = Bu1[(wb + 4 * t1 + krow) * 16];
#pragma unroll
    for (int c = 0; c < 4; ++c)
      aB[c] = *(const short8*)(xb + (size_t)(c * 16 + col) * H_DIM + ks0 + t1 * 32);
    // compute t0 from A buffers
    {
      short8 bg0, bg1, bu0, bu1;
#pragma unroll
      for (int j = 0; j < 8; ++j) {
        bg0[j] = f2bf((float)((g0A >> (4 * j)) & 15) * sg[0][g] - zg[0][g]);
        bg1[j] = f2bf((float)((g1A >> (4 * j)) & 15) * sg[1][g] - zg[1][g]);
        bu0[j] = f2bf((float)((u0A >> (4 * j)) & 15) * su[0][g] - zu[0][g]);
        bu1[j] = f2bf((float)((u1A >> (4 * j)) & 15) * su[1][g] - zu[1][g]);
      }
#pragma unroll
      for (int c = 0; c < 4; ++c) {
        accG[0][c] = __builtin_amdgcn_mfma_f32_16x16x32_bf16(aA[c], bg0, accG[0][c], 0, 0, 0);
        accG[1][c] = __builtin_amdgcn_mfma_f32_16x16x32_bf16(aA[c], bg1, accG[1][c], 0, 0, 0);
        accU[0][c] = __builtin_amdgcn_mfma_f32_16x16x32_bf16(aA[c], bu0, accU[0][c], 0, 0, 0);
        accU[1][c] = __builtin_amdgcn_mfma_f32_16x16x32_bf16(aA[c], bu1, accU[1][c], 0, 0, 0);
      }
    }
    // issue t2 -> A buffers
    g0A = Bg0[(wb + 4 * t2 + krow) * 16];
    g1A = Bg1[(wb + 4 * t2 + krow) * 16];
    u0A = Bu0[(wb + 4 * t2 + krow) * 16];
    u1A = Bu1[(wb + 4 * t2 + krow) * 16];
#pragma unroll
    for (int c = 0; c < 4; ++c)
      aA[c] = *(const short8*)(xb + (size_t)(c * 16 + col) * H_DIM + ks0 + t2 * 32);
    // compute t1 from B buffers
    {
      short8 bg0, bg1, bu0, bu1;
#pragma unroll
      for (int j = 0; j < 8; ++j) {
        bg0[j] = f2bf((float)((g0B >> (4 * j)) & 15) * sg[0][g] - zg[0][g]);
        bg1[j] = f2bf((float)((g1B >> (4 * j)) & 15) * sg[1][g] - zg[1][g]);
        bu0[j] = f2bf((float)((u0B >> (4 * j)) & 15) * su[0][g] - zu[0][g]);
        bu1[j] = f2bf((float)((u1B >> (4 * j)) & 15) * su[1][g] - zu[1][g]);
      }
#pragma unroll
      for (int c = 0; c < 4; ++c) {
        accG[0][c] = __builtin_amdgcn_mfma_f32_16x16x32_bf16(aB[c], bg0, accG[0][c], 0, 0, 0);
        accG[1][c] = __builtin_amdgcn_mfma_f32_16x16x32_bf16(aB[c], bg1, accG[1][c], 0, 0, 0);
        accU[0][c] = __builtin_amdgcn_mfma_f32_16x16x32_bf16(aB[c], bu0, accU[0][c], 0, 0, 0);
        accU[1][c] = __builtin_amdgcn_mfma_f32_16x16x32_bf16(aB[c], bu1, accU[1][c], 0, 0, 0);
      }
    }
  }

  // epilogue: per col-group: reduce gate, then up; silu; store bf16 h
  const int c2 = threadIdx.x >> 7;
  const int rh = (threadIdx.x >> 6) & 1;
  const int ll = threadIdx.x & 63;
#pragma unroll
  for (int cg = 0; cg < 2; ++cg) {
#pragma unroll
    for (int c = 0; c < 4; ++c)
#pragma unroll
      for (int r = 0; r < 4; ++r)
        red[w][c][r][l] = accG[cg][c][r];
    __syncthreads();
    float gsumr[2];
#pragma unroll
    for (int rr = 0; rr < 2; ++rr) {
      const int r = rh * 2 + rr;
      float s = 0.f;
#pragma unroll
      for (int ww = 0; ww < 8; ++ww) s += red[ww][c2][r][ll];
      gsumr[rr] = s;
    }
    __syncthreads();
#pragma unroll
    for (int c = 0; c < 4; ++c)
#pragma unroll
      for (int r = 0; r < 4; ++r)
        red[w][c][r][l] = accU[cg][c][r];
    __syncthreads();
#pragma unroll
    for (int rr = 0; rr < 2; ++rr) {
      const int r = rh * 2 + rr;
      float us = 0.f;
#pragma unroll
      for (int ww = 0; ww < 8; ++ww) us += red[ww][c2][r][ll];
      const float gv = gsumr[rr];
      const float hv = gv / (1.f + __expf(-gv)) * us;     // silu(g)*u
      const int m  = c2 * 16 + (ll >> 4) * 4 + r;         // C/D: row=(l>>4)*4+r
      const int ii = n0 + cg * 16 + (ll & 15);            //      col=l&15
      hb[(size_t)m * I_DIM + ii] = f2bf(hv);
    }
    if (cg == 0) __syncthreads();
  }
}

// ---- down GEMM, split-K x4 (transposed-packed) ----
__global__ __launch_bounds__(512, 4) void phase2p_kernel(
    const short* __restrict__ hb, const int* __restrict__ dpt,
    const float* __restrict__ dsc, const float* __restrict__ dze,
    float* __restrict__ part)
{
  __shared__ float red[8][4][4][64];   // 32 KB
  const int tile  = blockIdx.x & 255;
  const int split = blockIdx.x >> 8;
  const int n0   = tile * 16;
  const int w    = threadIdx.x >> 6;
  const int l    = threadIdx.x & 63;
  const int col  = l & 15;
  const int krow = l >> 4;
  const int n    = n0 + col;

  const int* dB = dpt + (size_t)tile * (KWI * 16) + col;

  f32x4 acc[4];
#pragma unroll
  for (int c = 0; c < 4; ++c)
#pragma unroll
    for (int r = 0; r < 4; ++r) acc[c][r] = 0.f;

  const int cnt    = (w < 6) ? 11 : 10;
  const int sstart = (w < 6) ? w * 11 : 66 + (w - 6) * 10;
  const int kbase  = split * 2752 + sstart * 32;
  const int wbase  = split * 344 + sstart * 4;

  const int g0 = kbase >> 7;
  float s0 = dsc[(size_t)n * NGI + g0];
  float s1 = dsc[(size_t)n * NGI + min(g0 + 1, NGI - 1)];
  float s2 = dsc[(size_t)n * NGI + min(g0 + 2, NGI - 1)];
  float s3 = dsc[(size_t)n * NGI + min(g0 + 3, NGI - 1)];
  float z0 = dze[(size_t)n * NGI + g0] * s0;
  float z1 = dze[(size_t)n * NGI + min(g0 + 1, NGI - 1)] * s1;
  float z2 = dze[(size_t)n * NGI + min(g0 + 2, NGI - 1)] * s2;
  float z3 = dze[(size_t)n * NGI + min(g0 + 3, NGI - 1)] * s3;

  int qdA = dB[(wbase + krow) * 16], qdB_;
  short8 aA[4], aB[4];
#pragma unroll
  for (int c = 0; c < 4; ++c)
    aA[c] = *(const short8*)(hb + (size_t)(c * 16 + col) * I_DIM + kbase + krow * 8);

  const int nh = cnt >> 1;
#pragma unroll 1
  for (int u = 0; u < nh; ++u) {
    const int t0 = 2 * u, t1 = 2 * u + 1;
    const int t2 = (t1 + 1 < cnt) ? (t1 + 1) : 0;
    qdB_ = dB[(wbase + 4 * t1 + krow) * 16];
#pragma unroll
    for (int c = 0; c < 4; ++c)
      aB[c] = *(const short8*)(hb + (size_t)(c * 16 + col) * I_DIM + kbase + t1 * 32 + krow * 8);
    {
      const int gi = ((kbase + t0 * 32) >> 7) - g0;
      const float sv = gi == 0 ? s0 : gi == 1 ? s1 : gi == 2 ? s2 : s3;
      const float zv = gi == 0 ? z0 : gi == 1 ? z1 : gi == 2 ? z2 : z3;
      short8 b;
#pragma unroll
      for (int j = 0; j < 8; ++j)
        b[j] = f2bf((float)((qdA >> (4 * j)) & 15) * sv - zv);
#pragma unroll
      for (int c = 0; c < 4; ++c)
        acc[c] = __builtin_amdgcn_mfma_f32_16x16x32_bf16(aA[c], b, acc[c], 0, 0, 0);
    }
    qdA = dB[(wbase + 4 * t2 + krow) * 16];
#pragma unroll
    for (int c = 0; c < 4; ++c)
      aA[c] = *(const short8*)(hb + (size_t)(c * 16 + col) * I_DIM + kbase + t2 * 32 + krow * 8);
    {
      const int gi = ((kbase + t1 * 32) >> 7) - g0;
      const float sv = gi == 0 ? s0 : gi == 1 ? s1 : gi == 2 ? s2 : s3;
      const float zv = gi == 0 ? z0 : gi == 1 ? z1 : gi == 2 ? z2 : z3;
      short8 b;
#pragma unroll
      for (int j = 0; j < 8; ++j)
        b[j] = f2bf((float)((qdB_ >> (4 * j)) & 15) * sv - zv);
#pragma unroll
      for (int c = 0; c < 4; ++c)
        acc[c] = __builtin_amdgcn_mfma_f32_16x16x32_bf16(aB[c], b, acc[c], 0, 0, 0);
    }
  }
  if (cnt & 1) {
    const int t0 = cnt - 1;
    const int gi = ((kbase + t0 * 32) >> 7) - g0;
    const float sv = gi == 0 ? s0 : gi == 1 ? s1 : gi == 2 ? s2 : s3;
    const float zv = gi == 0 ? z0 : gi == 1 ? z1 : gi == 2 ? z2 : z3;
    short8 b;
#pragma unroll
    for (int j = 0; j < 8; ++j)
      b[j] = f2bf((float)((qdA >> (4 * j)) & 15) * sv - zv);
#pragma unroll
    for (int c = 0; c < 4; ++c)
      acc[c] = __builtin_amdgcn_mfma_f32_16x16x32_bf16(aA[c], b, acc[c], 0, 0, 0);
  }

#pragma unroll
  for (int c = 0; c < 4; ++c)
#pragma unroll
    for (int r = 0; r < 4; ++r)
      red[w][c][r][l] = acc[c][r];
  __syncthreads();

  if (threadIdx.x < 256) {
    const int c2 = threadIdx.x >> 6;
    const int ll = threadIdx.x & 63;
    float* po = part + (size_t)split * (64 * H_DIM);
#pragma unroll
    for (int r = 0; r < 4; ++r) {
      float s = 0.f;
#pragma unroll
      for (int ww = 0; ww < 8; ++ww) s += red[ww][c2][r][ll];
      const int m  = c2 * 16 + (ll >> 4) * 4 + r;
      const int nn = n0 + (ll & 15);
      po[(size_t)m * H_DIM + nn] = s;
    }
  }
}

__global__ void reduce4_kernel(const float* __restrict__ part, float* __restrict__ out) {
  const int idx = (blockIdx.x * 256 + threadIdx.x) * 4;
  const int S = 64 * H_DIM;
  f32x4 s0 = *(const f32x4*)(part + idx);
  f32x4 s1 = *(const f32x4*)(part + S + idx);
  f32x4 s2 = *(const f32x4*)(part + 2 * S + idx);
  f32x4 s3 = *(const f32x4*)(part + 3 * S + idx);
  f32x4 r = (s0 + s1) + (s2 + s3);
  *(f32x4*)(out + idx) = r;
}

// ---------------- fallback (raw-weight) kernels, used if ws too small --------
__global__ void xcvt_kernel(const float* __restrict__ x, short* __restrict__ xb) {
  int i = (blockIdx.x * 256 + threadIdx.x) * 4;
  f32x4 v = *(const f32x4*)(x + i);
  s16x4 o;
  o[0] = f2bf(v[0]); o[1] = f2bf(v[1]); o[2] = f2bf(v[2]); o[3] = f2bf(v[3]);
  *(s16x4*)(xb + i) = o;
}

__global__ __launch_bounds__(512, 4) void phase1f_kernel(
    const short* __restrict__ xb,
    const int* __restrict__ gq, const float* __restrict__ gsc, const float* __restrict__ gze,
    const int* __restrict__ uq, const float* __restrict__ usc, const float* __restrict__ uze,
    short* __restrict__ hb)
{
  __shared__ float red[8][4][4][64];
  const int n0   = blockIdx.x * 16;
  const int w    = threadIdx.x >> 6;
  const int l    = threadIdx.x & 63;
  const int col  = l & 15;
  const int krow = l >> 4;
  const int i    = n0 + col;
  const int*   gqr = gq + (size_t)i * H_DIM;
  const int*   uqr = uq + (size_t)i * H_DIM;
  const float* gsr = gsc + (size_t)i * NGH;
  const float* gzr = gze + (size_t)i * NGH;
  const float* usr = usc + (size_t)i * NGH;
  const float* uzr = uze + (size_t)i * NGH;
  f32x4 accG[4], accU[4];
#pragma unroll
  for (int c = 0; c < 4; ++c)
#pragma unroll
    for (int r = 0; r < 4; ++r) { accG[c][r] = 0.f; accU[c][r] = 0.f; }
  const int kw = w * 512;
#pragma unroll 1
  for (int g = 0; g < 4; ++g) {
    const int gg = w * 4 + g;
    const float sg = gsr[gg], zg = gzr[gg] * sg;
    const float su = usr[gg], zu = uzr[gg] * su;
#pragma unroll
    for (int ks = 0; ks < 4; ++ks) {
      const int koff = kw + g * 128 + ks * 32 + krow * 8;
      i32x4 q0 = *(const i32x4*)(gqr + koff);
      i32x4 q1 = *(const i32x4*)(gqr + koff + 4);
      i32x4 p0 = *(const i32x4*)(uqr + koff);
      i32x4 p1 = *(const i32x4*)(uqr + koff + 4);
      short8 a[4];
#pragma unroll
      for (int c = 0; c < 4; ++c)
        a[c] = *(const short8*)(xb + (size_t)(c * 16 + col) * H_DIM + koff);
      short8 bg, bu;
#pragma unroll
      for (int j = 0; j < 4; ++j) {
        bg[j]     = f2bf((float)q0[j] * sg - zg);
        bg[j + 4] = f2bf((float)q1[j] * sg - zg);
        bu[j]     = f2bf((float)p0[j] * su - zu);
        bu[j + 4] = f2bf((float)p1[j] * su - zu);
      }
#pragma unroll
      for (int c = 0; c < 4; ++c) {
        accG[c] = __builtin_amdgcn_mfma_f32_16x16x32_bf16(a[c], bg, accG[c], 0, 0, 0);
        accU[c] = __builtin_amdgcn_mfma_f32_16x16x32_bf16(a[c], bu, accU[c], 0, 0, 0);
      }
    }
  }
  const int c2 = threadIdx.x >> 7;
  const int rh = (threadIdx.x >> 6) & 1;
  const int ll = threadIdx.x & 63;
#pragma unroll
  for (int c = 0; c < 4; ++c)
#pragma unroll
    for (int r = 0; r < 4; ++r)
      red[w][c][r][l] = accG[c][r];
  __syncthreads();
  float gsum[2];
#pragma unroll
  for (int rr = 0; rr < 2; ++rr) {
    const int r = rh * 2 + rr;
    float s = 0.f;
#pragma unroll
    for (int ww = 0; ww < 8; ++ww) s += red[ww][c2][r][ll];
    gsum[rr] = s;
  }
  __syncthreads();
#pragma unroll
  for (int c = 0; c < 4; ++c)
#pragma unroll
    for (int r = 0; r < 4; ++r)
      red[w][c][r][l] = accU[c][r];
  __syncthreads();
#pragma unroll
  for (int rr = 0; rr < 2; ++rr) {
    const int r = rh * 2 + rr;
    float us = 0.f;
#pragma unroll
    for (int ww = 0; ww < 8; ++ww) us += red[ww][c2][r][ll];
    const float gv = gsum[rr];
    const float hv = gv / (1.f + __expf(-gv)) * us;
    const int m  = c2 * 16 + (ll >> 4) * 4 + r;
    const int ii = n0 + (ll & 15);
    hb[(size_t)m * I_DIM + ii] = f2bf(hv);
  }
}

__global__ __launch_bounds__(512, 4) void phase2f_kernel(
    const short* __restrict__ hb,
    const int* __restrict__ dq, const float* __restrict__ dsc, const float* __restrict__ dze,
    float* __restrict__ part)
{
  __shared__ float red[8][4][4][64];
  const int tile  = blockIdx.x & 255;
  const int split = blockIdx.x >> 8;
  const int n0   = tile * 16;
  const int w    = threadIdx.x >> 6;
  const int l    = threadIdx.x & 63;
  const int col  = l & 15;
  const int krow = l >> 4;
  const int n    = n0 + col;
  const int*   dqr = dq + (size_t)n * I_DIM;
  const float* dsr = dsc + (size_t)n * NGI;
  const float* dzr = dze + (size_t)n * NGI;
  f32x4 acc[4];
#pragma unroll
  for (int c = 0; c < 4; ++c)
#pragma unroll
    for (int r = 0; r < 4; ++r) acc[c][r] = 0.f;
  const int cnt    = (w < 6) ? 11 : 10;
  const int sstart = (w < 6) ? w * 11 : 66 + (w - 6) * 10;
  const int kbase  = split * 2752 + sstart * 32;
  int gprev = -1;
  float sv = 0.f, zv = 0.f;
#pragma unroll 1
  for (int s = 0; s < cnt; ++s) {
    const int k0 = kbase + s * 32;
    const int g  = k0 >> 7;
    if (g != gprev) { sv = dsr[g]; zv = dzr[g] * sv; gprev = g; }
    i32x4 q0 = *(const i32x4*)(dqr + k0 + krow * 8);
    i32x4 q1 = *(const i32x4*)(dqr + k0 + krow * 8 + 4);
    short8 a[4];
#pragma unroll
    for (int c = 0; c < 4; ++c)
      a[c] = *(const short8*)(hb + (size_t)(c * 16 + col) * I_DIM + k0 + krow * 8);
    short8 b;
#pragma unroll
    for (int j = 0; j < 4; ++j) {
      b[j]     = f2bf((float)q0[j] * sv - zv);
      b[j + 4] = f2bf((float)q1[j] * sv - zv);
    }
#pragma unroll
    for (int c = 0; c < 4; ++c)
      acc[c] = __builtin_amdgcn_mfma_f32_16x16x32_bf16(a[c], b, acc[c], 0, 0, 0);
  }
#pragma unroll
  for (int c = 0; c < 4; ++c)
#pragma unroll
    for (int r = 0; r < 4; ++r)
      red[w][c][r][l] = acc[c][r];
  __syncthreads();
  if (threadIdx.x < 256) {
    const int c2 = threadIdx.x >> 6;
    const int ll = threadIdx.x & 63;
    float* po = part + (size_t)split * (64 * H_DIM);
#pragma unroll
    for (int r = 0; r < 4; ++r) {
      float s = 0.f;
#pragma unroll
      for (int ww = 0; ww < 8; ++ww) s += red[ww][c2][r][ll];
      const int m  = c2 * 16 + (ll >> 4) * 4 + r;
      const int nn = n0 + (ll & 15);
      po[(size_t)m * H_DIM + nn] = s;
    }
  }
}

extern "C" void kernel_launch(void* const* d_in, const int* in_sizes, int n_in,
                              void* d_out, int out_size, void* d_ws, size_t ws_size,
                              hipStream_t stream) {
  const float* x  = (const float*)d_in[0];
  const int*   gq = (const int*)d_in[1];
  const float* gs = (const float*)d_in[2];
  const float* gz = (const float*)d_in[3];
  const int*   uq = (const int*)d_in[4];
  const float* us = (const float*)d_in[5];
  const float* uz = (const float*)d_in[6];
  const int*   dq = (const int*)d_in[7];
  const float* ds = (const float*)d_in[8];
  const float* dz = (const float*)d_in[9];
  float* out = (float*)d_out;

  const size_t XB   = (size_t)64 * H_DIM * 2;          // 512 KB
  const size_t HB   = (size_t)64 * I_DIM * 2;          // 1.376 MB
  const size_t PART = (size_t)4 * 64 * H_DIM * 4;      // 4 MB
  const size_t PK   = (size_t)NWV * 4;                 // 22.5 MB each

  short* xb   = (short*)d_ws;
  short* hb   = (short*)((char*)d_ws + XB);
  float* part = (float*)((char*)d_ws + XB + HB);
  int*   pkt  = (int*)((char*)d_ws + XB + HB + PART);  // [gate | up | down]
  int*   gp   = pkt;
  int*   upk  = pkt + (size_t)NWV;
  int*   dpk  = pkt + 2 * (size_t)NWV;

  if (ws_size >= XB + HB + PART + 3 * PK) {
    packall_kernel<<<33024 + 256, 256, 0, stream>>>(gq, uq, dq, pkt, x, xb);
    gemm_gu_fused<<<344, 512, 0, stream>>>(xb, gp, upk, gs, gz, us, uz, hb);
    phase2p_kernel<<<(H_DIM / 16) * 4, 512, 0, stream>>>(hb, dpk, ds, dz, part);
  } else {
    xcvt_kernel<<<(64 * H_DIM) / 1024, 256, 0, stream>>>(x, xb);
    phase1f_kernel<<<I_DIM / 16, 512, 0, stream>>>(xb, gq, gs, gz, uq, us, uz, hb);
    phase2f_kernel<<<(H_DIM / 16) * 4, 512, 0, stream>>>(hb, dq, ds, dz, part);
  }
  reduce4_kernel<<<(64 * H_DIM) / 1024, 256, 0, stream>>>(part, out);
}